// Round 6
// baseline (691.583 us; speedup 1.0000x reference)
//
#include <hip/hip_runtime.h>
#include <hip/hip_bf16.h>
#include <math.h>

#define T_TOK 4096
#define D_DIM 1024
#define E_EXP 8
#define FF_DIM 4096
#define NROWS (T_TOK * 2)
#define MAXT 40   // max m-tiles (BM=256): 8192/256 + 8

typedef unsigned short u16;
typedef unsigned int u32;
typedef __attribute__((ext_vector_type(8))) short bf16x8;
typedef __attribute__((ext_vector_type(4))) float f32x4;
typedef __attribute__((ext_vector_type(4))) short s16x4;

__device__ __forceinline__ u16 f2bf(float f) {
    union { float f; unsigned u; } v; v.f = f;
    unsigned r = v.u + 0x7FFFu + ((v.u >> 16) & 1u);
    return (u16)(r >> 16);
}

typedef const __attribute__((address_space(1))) u32* gas1_t;
typedef __attribute__((address_space(3))) u32* las3_t;
#define GLOAD16(g, l) __builtin_amdgcn_global_load_lds((gas1_t)(const void*)(g), (las3_t)(void*)(l), 16, 0, 0)
#define MFMA(a, b, c) __builtin_amdgcn_mfma_f32_16x16x32_bf16((a), (b), (c), 0, 0, 0)
#define CFENCE() asm volatile("" ::: "memory")

// ---------------- small kernels ----------------

__global__ void k_init(int* cnt, float* probsum) {
    int i = threadIdx.x;
    if (i < E_EXP) { cnt[i] = 0; probsum[i] = 0.f; }
}

__global__ __launch_bounds__(256) void k_router(
    const float* __restrict__ x, const float* __restrict__ Wr,
    int* __restrict__ tok_e, float* __restrict__ tok_w,
    int* __restrict__ cnt, float* __restrict__ probsum)
{
    __shared__ float bp[E_EXP];
    __shared__ int   bc[E_EXP];
    const int tid = threadIdx.x;
    if (tid < E_EXP) { bp[tid] = 0.f; bc[tid] = 0; }
    __syncthreads();
    const int wave = tid >> 6, lane = tid & 63;
    const int t = blockIdx.x * 4 + wave;
    const float* xt = x + (size_t)t * D_DIM;
    float a[E_EXP] = {0.f,0.f,0.f,0.f,0.f,0.f,0.f,0.f};
    for (int j = lane; j < D_DIM; j += 64) {
        float xv = xt[j];
        #pragma unroll
        for (int e = 0; e < E_EXP; e++) a[e] = fmaf(xv, Wr[e * D_DIM + j], a[e]);
    }
    #pragma unroll
    for (int e = 0; e < E_EXP; e++) {
        #pragma unroll
        for (int off = 32; off; off >>= 1) a[e] += __shfl_xor(a[e], off, 64);
    }
    if (lane == 0) {
        float mx = a[0];
        #pragma unroll
        for (int e = 1; e < E_EXP; e++) mx = fmaxf(mx, a[e]);
        float p[E_EXP], s = 0.f;
        #pragma unroll
        for (int e = 0; e < E_EXP; e++) { p[e] = expf(a[e] - mx); s += p[e]; }
        float inv = 1.f / s;
        #pragma unroll
        for (int e = 0; e < E_EXP; e++) { p[e] *= inv; atomicAdd(&bp[e], p[e]); }
        int e0 = 0; float v0 = p[0];
        #pragma unroll
        for (int e = 1; e < E_EXP; e++) if (p[e] > v0) { v0 = p[e]; e0 = e; }
        int e1 = -1; float v1 = -1.f;
        #pragma unroll
        for (int e = 0; e < E_EXP; e++) if (e != e0 && p[e] > v1) { v1 = p[e]; e1 = e; }
        float sv = v0 + v1 + 1e-6f;
        tok_e[2*t] = e0; tok_e[2*t+1] = e1;
        tok_w[2*t] = v0 / sv; tok_w[2*t+1] = v1 / sv;
        atomicAdd(&bc[e0], 1); atomicAdd(&bc[e1], 1);
    }
    __syncthreads();
    if (tid < E_EXP) { atomicAdd(&cnt[tid], bc[tid]); atomicAdd(&probsum[tid], bp[tid]); }
}

__global__ void k_prefix(const int* __restrict__ cnt, const float* __restrict__ probsum,
                         int* __restrict__ basep, int* __restrict__ cursor,
                         float* __restrict__ out_lb,
                         int* __restrict__ nt, int* __restrict__ te, int* __restrict__ tm)
{
    if (threadIdx.x == 0) {
        int b = 0; float lb = 0.f;
        for (int e = 0; e < E_EXP; e++) {
            basep[e] = b; b += cnt[e];
            lb += ((float)cnt[e] / (8192.f + 1e-6f)) * probsum[e];
        }
        *out_lb = lb * (float)E_EXP;
        int n1 = 0;
        for (int e = 0; e < E_EXP; e++)
            for (int m = 0; m < cnt[e]; m += 256) { te[n1] = e; tm[n1] = m; n1++; }
        *nt = n1;
    }
    if (threadIdx.x < E_EXP) cursor[threadIdx.x] = 0;
}

__global__ void k_assign(const int* __restrict__ tok_e, const float* __restrict__ tok_w,
                         const int* __restrict__ basep, int* __restrict__ cursor,
                         int* __restrict__ row_token, int* __restrict__ row_slot,
                         float* __restrict__ row_weight)
{
    int t = blockIdx.x * blockDim.x + threadIdx.x;
    if (t >= T_TOK) return;
    #pragma unroll
    for (int k = 0; k < 2; k++) {
        int e = tok_e[2*t + k];
        int pos = basep[e] + atomicAdd(&cursor[e], 1);
        row_token[pos] = t; row_slot[pos] = k; row_weight[pos] = tok_w[2*t + k];
    }
}

// ---------------- conversion kernels ----------------

__global__ __launch_bounds__(256) void k_cvt_x(const float* __restrict__ in, u16* __restrict__ out) {
    size_t i = ((size_t)blockIdx.x * 256 + threadIdx.x) * 8;
    f32x4 a = *(const f32x4*)(in + i);
    f32x4 b = *(const f32x4*)(in + i + 4);
    bf16x8 o;
    #pragma unroll
    for (int j = 0; j < 4; j++) { o[j] = (short)f2bf(a[j]); o[j + 4] = (short)f2bf(b[j]); }
    *(bf16x8*)(out + i) = o;
}

__device__ __forceinline__ void tile_transpose(const float* __restrict__ in, u16* __restrict__ out,
                                               int R, int C) {
    __shared__ u16 t[64][68];
    const int r0 = blockIdx.y * 64, c0 = blockIdx.x * 64;
    const int tid = threadIdx.x;
    const int lr = tid >> 4, lc = (tid & 15) * 4;
    #pragma unroll
    for (int i = 0; i < 4; i++) {
        const int r = lr + i * 16;
        f32x4 v = *(const f32x4*)(in + (size_t)(r0 + r) * C + c0 + lc);
        s16x4 w;
        #pragma unroll
        for (int j = 0; j < 4; j++) w[j] = (short)f2bf(v[j]);
        *(s16x4*)&t[r][lc] = w;
    }
    __syncthreads();
    #pragma unroll
    for (int i = 0; i < 4; i++) {
        const int c = lr + i * 16;
        s16x4 w;
        #pragma unroll
        for (int j = 0; j < 4; j++) w[j] = (short)t[lc + j][c];
        *(s16x4*)(out + (size_t)(c0 + c) * R + r0 + lc) = w;
    }
}

__global__ __launch_bounds__(256) void k_cvt_wt(const float* __restrict__ W1, const float* __restrict__ Wg,
                                                u16* __restrict__ w1t, u16* __restrict__ wgt) {
    const int z = blockIdx.z;
    const float* in;
    u16* out;
    if (z < E_EXP) { in = W1 + (size_t)z * D_DIM * FF_DIM; out = w1t + (size_t)z * D_DIM * FF_DIM; }
    else { in = Wg + (size_t)(z - E_EXP) * D_DIM * FF_DIM; out = wgt + (size_t)(z - E_EXP) * D_DIM * FF_DIM; }
    tile_transpose(in, out, D_DIM, FF_DIM);
}

__global__ __launch_bounds__(256) void k_cvt_w2(const float* __restrict__ W2, u16* __restrict__ w2t) {
    const int z = blockIdx.z;
    tile_transpose(W2 + (size_t)z * FF_DIM * D_DIM, w2t + (size_t)z * FF_DIM * D_DIM, FF_DIM, D_DIM);
}

// ---------------- pass 1: hg = silu(x@Wg) * (x@W1) ----------------
// BM=256, BN=128, BK=32, 8 waves (2M x 4N).
// LDS tiles stored CHUNK-MAJOR (K-outer): addr(row, ch) = (ch*NR + row)*16B.
//   -> MFMA fragment reads (16 consecutive rows, fixed chunk) are 256 contiguous
//      bytes per q-group: zero bank conflicts, no swizzle needed. Staging stays
//      linear: thread t covers piece p=t (ch=p>>8,row=p&255), dest = base+t*16B.
// 3 LDS buffers, prefetch distance 2, counted vmcnt (never 0 in steady state).

__global__ __launch_bounds__(512, 2) void k_pass1(
    const u16* __restrict__ xbf,
    const u16* __restrict__ w1t, const u16* __restrict__ wgt,
    const float* __restrict__ b1v, const float* __restrict__ bgv,
    const int* __restrict__ cnt, const int* __restrict__ basep,
    const int* __restrict__ row_token,
    const int* __restrict__ ntp, const int* __restrict__ te, const int* __restrict__ tm,
    u16* __restrict__ hg)
{
    const int ty = blockIdx.y;
    if (ty >= *ntp) return;
    const int e = te[ty];
    const int m0 = tm[ty];
    const int count = cnt[e];
    const int rbase = basep[e];
    const int n0 = blockIdx.x * 128;

    // per buffer (16384 elems = 32 KB): A @0 (8192), Bh @8192 (4096), Bg @12288 (4096)
    __shared__ __align__(16) u16 LDS[3 * 16384];

    const int tid = threadIdx.x;
    const int l = tid & 63;
    const int w = tid >> 6;

    // A staging: thread t covers (row = t&255, chunks (t>>8)*2 and (t>>8)*2+... )
    // pieces p = t (ch = t>>8 in {0,1}) and p = t+512 (ch = t>>8 + 2)
    const int arow = tid & 255;
    const int ach = (tid >> 8) * 8;          // elem offset of first chunk (0 or 8)
    int gA = m0 + arow; if (gA > count - 1) gA = count - 1;
    const u16* sA = xbf + (size_t)row_token[rbase + gA] * D_DIM + ach;
    const int dA0 = tid * 8;                 // elems
    const int dA1 = tid * 8 + 4096;

    // B staging: thread t covers piece p=t: (row = t&127, ch = t>>7)
    const int brow = tid & 127;
    const int bch = (tid >> 7) * 8;
    const size_t wo = ((size_t)e * FF_DIM + (size_t)(n0 + brow)) * D_DIM + bch;
    const u16* sBh = w1t + wo;
    const u16* sBg = wgt + wo;
    const int dB = tid * 8;

    const int wm = w >> 2, wn = w & 3;       // 2M x 4N
    const int fr = l & 15, q = l >> 4;
    // fragment read offsets (chunk-major): A: q*2048 + row*8 ; B: base + q*1024 + row*8

    f32x4 acc_h[8][2], acc_g[8][2];
    const f32x4 z4 = {0.f, 0.f, 0.f, 0.f};
    #pragma unroll
    for (int mf = 0; mf < 8; mf++)
        #pragma unroll
        for (int nf = 0; nf < 2; nf++) { acc_h[mf][nf] = z4; acc_g[mf][nf] = z4; }

    auto STAGE_A = [&](int b, int k0) {
        GLOAD16(sA + k0,      &LDS[b * 16384 + dA0]);
        GLOAD16(sA + k0 + 16, &LDS[b * 16384 + dA1]);
    };
    auto STAGE_B = [&](int b, int k0) {
        GLOAD16(sBh + k0, &LDS[b * 16384 + 8192 + dB]);
        GLOAD16(sBg + k0, &LDS[b * 16384 + 12288 + dB]);
    };

    const int NT = D_DIM / 32;   // 32
    STAGE_A(0, 0); STAGE_B(0, 0);
    STAGE_A(1, 32); STAGE_B(1, 32);
    int cur = 0;
    #pragma unroll 1
    for (int t = 0; t < NT; ++t) {
        const int nx = (cur + 2 >= 3) ? cur - 1 : cur + 2;
        const int k2 = (t + 2) * 32;
        // ---- phase 0 ----
        if (t + 2 < NT) {
            STAGE_A(nx, k2);
            asm volatile("s_waitcnt vmcnt(6)" ::: "memory");
        } else if (t + 1 < NT) {
            asm volatile("s_waitcnt vmcnt(4)" ::: "memory");
        } else {
            asm volatile("s_waitcnt vmcnt(0)" ::: "memory");
        }
        __builtin_amdgcn_s_barrier();
        CFENCE();
        const int ab = cur * 16384;
        bf16x8 bh[2], bg[2], a0[4];
        #pragma unroll
        for (int nf = 0; nf < 2; nf++) {
            const int row = wn * 32 + nf * 16 + fr;
            bh[nf] = *(const bf16x8*)&LDS[ab + 8192  + q * 1024 + row * 8];
            bg[nf] = *(const bf16x8*)&LDS[ab + 12288 + q * 1024 + row * 8];
        }
        #pragma unroll
        for (int i = 0; i < 4; i++)
            a0[i] = *(const bf16x8*)&LDS[ab + q * 2048 + (wm * 128 + i * 16 + fr) * 8];
        __builtin_amdgcn_s_setprio(1);
        #pragma unroll
        for (int i = 0; i < 4; i++) {
            acc_h[i][0] = MFMA(a0[i], bh[0], acc_h[i][0]);
            acc_h[i][1] = MFMA(a0[i], bh[1], acc_h[i][1]);
            acc_g[i][0] = MFMA(a0[i], bg[0], acc_g[i][0]);
            acc_g[i][1] = MFMA(a0[i], bg[1], acc_g[i][1]);
        }
        __builtin_amdgcn_s_setprio(0);
        // ---- phase 1 ----
        if (t + 2 < NT) STAGE_B(nx, k2);
        bf16x8 a1[4];
        #pragma unroll
        for (int i = 0; i < 4; i++)
            a1[i] = *(const bf16x8*)&LDS[ab + q * 2048 + (wm * 128 + (4 + i) * 16 + fr) * 8];
        __builtin_amdgcn_s_setprio(1);
        #pragma unroll
        for (int i = 0; i < 4; i++) {
            acc_h[4 + i][0] = MFMA(a1[i], bh[0], acc_h[4 + i][0]);
            acc_h[4 + i][1] = MFMA(a1[i], bh[1], acc_h[4 + i][1]);
            acc_g[4 + i][0] = MFMA(a1[i], bg[0], acc_g[4 + i][0]);
            acc_g[4 + i][1] = MFMA(a1[i], bg[1], acc_g[4 + i][1]);
        }
        __builtin_amdgcn_s_setprio(0);
        CFENCE();
        __builtin_amdgcn_s_barrier();
        cur = (cur + 1 >= 3) ? 0 : cur + 1;
    }

    const float* b1p = b1v + (size_t)e * FF_DIM + n0;
    const float* bgp = bgv + (size_t)e * FF_DIM + n0;
    #pragma unroll
    for (int mf = 0; mf < 8; mf++) {
        const int rl = wm * 128 + mf * 16 + q * 4;
        #pragma unroll
        for (int r = 0; r < 4; r++) {
            const int g = m0 + rl + r;
            if (g < count) {
                u16* orow = hg + (size_t)(rbase + g) * FF_DIM + n0;
                #pragma unroll
                for (int nf = 0; nf < 2; nf++) {
                    const int col = wn * 32 + nf * 16 + fr;
                    float hv = acc_h[mf][nf][r] + b1p[col];
                    float gv = acc_g[mf][nf][r] + bgp[col];
                    float sig = 1.f / (1.f + expf(-gv));
                    orow[col] = f2bf(gv * sig * hv);
                }
            }
        }
    }
}

// ---------------- pass 2: contrib = w * (hg @ W2 + b2) ----------------
// BM=256, BN=128, BK=32, 8 waves (4M x 2N). Same chunk-major layout + pipeline.

__global__ __launch_bounds__(512, 2) void k_pass2(
    const u16* __restrict__ hg,
    const u16* __restrict__ w2t, const float* __restrict__ b2v,
    const int* __restrict__ cnt, const int* __restrict__ basep,
    const int* __restrict__ row_token, const int* __restrict__ row_slot,
    const float* __restrict__ row_weight,
    const int* __restrict__ ntp, const int* __restrict__ te, const int* __restrict__ tm,
    float* __restrict__ contrib)
{
    const int ty = blockIdx.y;
    if (ty >= *ntp) return;
    const int e = te[ty];
    const int m0 = tm[ty];
    const int count = cnt[e];
    const int rbase = basep[e];
    const int n0 = blockIdx.x * 128;

    // per buffer (12288 elems = 24 KB): A @0 (8192), B @8192 (4096)
    __shared__ __align__(16) u16 LDS[3 * 12288];

    const int tid = threadIdx.x;
    const int l = tid & 63;
    const int w = tid >> 6;

    const int arow = tid & 255;
    const int ach = (tid >> 8) * 8;
    int gA = m0 + arow; if (gA > count - 1) gA = count - 1;
    const u16* sA = hg + (size_t)(rbase + gA) * FF_DIM + ach;
    const int dA0 = tid * 8;
    const int dA1 = tid * 8 + 4096;

    const int brow = tid & 127;
    const int bch = (tid >> 7) * 8;
    const u16* sB = w2t + ((size_t)e * D_DIM + (size_t)(n0 + brow)) * FF_DIM + bch;
    const int dB = tid * 8;

    const int wm = w >> 1, wn = w & 1;     // 4M x 2N
    const int fr = l & 15, q = l >> 4;

    f32x4 acc[4][4];
    const f32x4 z4 = {0.f, 0.f, 0.f, 0.f};
    #pragma unroll
    for (int mf = 0; mf < 4; mf++)
        #pragma unroll
        for (int nf = 0; nf < 4; nf++) acc[mf][nf] = z4;

    auto STAGE = [&](int b, int k0) {
        GLOAD16(sA + k0,      &LDS[b * 12288 + dA0]);
        GLOAD16(sA + k0 + 16, &LDS[b * 12288 + dA1]);
        GLOAD16(sB + k0,      &LDS[b * 12288 + 8192 + dB]);
    };

    const int NT = FF_DIM / 32;   // 128
    STAGE(0, 0);
    STAGE(1, 32);
    int cur = 0;
    #pragma unroll 1
    for (int t = 0; t < NT; ++t) {
        const int nx = (cur + 2 >= 3) ? cur - 1 : cur + 2;
        if (t + 2 < NT) {
            STAGE(nx, (t + 2) * 32);
            asm volatile("s_waitcnt vmcnt(6)" ::: "memory");
        } else if (t + 1 < NT) {
            asm volatile("s_waitcnt vmcnt(3)" ::: "memory");
        } else {
            asm volatile("s_waitcnt vmcnt(0)" ::: "memory");
        }
        __builtin_amdgcn_s_barrier();
        CFENCE();
        const int ab = cur * 12288;
        bf16x8 a[4], bb[4];
        #pragma unroll
        for (int mf = 0; mf < 4; mf++)
            a[mf] = *(const bf16x8*)&LDS[ab + q * 2048 + (wm * 64 + mf * 16 + fr) * 8];
        #pragma unroll
        for (int nf = 0; nf < 4; nf++)
            bb[nf] = *(const bf16x8*)&LDS[ab + 8192 + q * 1024 + (wn * 64 + nf * 16 + fr) * 8];
        __builtin_amdgcn_s_setprio(1);
        #pragma unroll
        for (int mf = 0; mf < 4; mf++)
            #pragma unroll
            for (int nf = 0; nf < 4; nf++)
                acc[mf][nf] = MFMA(a[mf], bb[nf], acc[mf][nf]);
        __builtin_amdgcn_s_setprio(0);
        CFENCE();
        __builtin_amdgcn_s_barrier();
        cur = (cur + 1 >= 3) ? 0 : cur + 1;
    }

    const float* b2p = b2v + (size_t)e * D_DIM + n0;
    #pragma unroll
    for (int mf = 0; mf < 4; mf++) {
        const int rl = wm * 64 + mf * 16 + q * 4;
        #pragma unroll
        for (int r = 0; r < 4; r++) {
            const int g = m0 + rl + r;
            if (g < count) {
                const int token = row_token[rbase + g];
                const int slot  = row_slot[rbase + g];
                const float wgt_ = row_weight[rbase + g];
                float* orow = contrib + ((size_t)slot * T_TOK + token) * D_DIM + n0;
                #pragma unroll
                for (int nf = 0; nf < 4; nf++) {
                    const int col = wn * 64 + nf * 16 + fr;
                    orow[col] = wgt_ * (acc[mf][nf][r] + b2p[col]);
                }
            }
        }
    }
}

__global__ void k_combine(const float* __restrict__ contrib, float* __restrict__ out) {
    int i = blockIdx.x * blockDim.x + threadIdx.x;
    const f32x4* c0 = (const f32x4*)contrib;
    const f32x4* c1 = c0 + ((size_t)T_TOK * D_DIM / 4);
    f32x4* o = (f32x4*)out;
    o[i] = c0[i] + c1[i];
}

// ---------------- launch ----------------

extern "C" void kernel_launch(void* const* d_in, const int* in_sizes, int n_in,
                              void* d_out, int out_size, void* d_ws, size_t ws_size,
                              hipStream_t stream)
{
    (void)in_sizes; (void)n_in; (void)out_size; (void)ws_size;
    const float* x  = (const float*)d_in[0];
    const float* Wr = (const float*)d_in[1];
    const float* W1 = (const float*)d_in[2];
    const float* b1 = (const float*)d_in[3];
    const float* Wg = (const float*)d_in[4];
    const float* bg = (const float*)d_in[5];
    const float* W2 = (const float*)d_in[6];
    const float* b2 = (const float*)d_in[7];
    float* out = (float*)d_out;

    char* ws = (char*)d_ws;
    u16* xbf = (u16*)ws;             ws += (size_t)T_TOK * D_DIM * sizeof(u16);
    u16* w1t = (u16*)ws;             ws += (size_t)E_EXP * D_DIM * FF_DIM * sizeof(u16);
    u16* wgt = (u16*)ws;             ws += (size_t)E_EXP * D_DIM * FF_DIM * sizeof(u16);
    u16* w2t = (u16*)ws;             ws += (size_t)E_EXP * D_DIM * FF_DIM * sizeof(u16);
    u16* hg = (u16*)ws;              ws += (size_t)NROWS * FF_DIM * sizeof(u16);
    int* tok_e = (int*)ws;           ws += (size_t)T_TOK * 2 * sizeof(int);
    float* tok_w = (float*)ws;       ws += (size_t)T_TOK * 2 * sizeof(float);
    int* row_token = (int*)ws;       ws += (size_t)NROWS * sizeof(int);
    int* row_slot = (int*)ws;        ws += (size_t)NROWS * sizeof(int);
    float* row_weight = (float*)ws;  ws += (size_t)NROWS * sizeof(float);
    int* cnt = (int*)ws;             ws += 8 * sizeof(int);
    int* basep = (int*)ws;           ws += 8 * sizeof(int);
    int* cursor = (int*)ws;          ws += 8 * sizeof(int);
    float* probsum = (float*)ws;     ws += 8 * sizeof(float);
    int* nt = (int*)ws;              ws += sizeof(int);
    int* te = (int*)ws;              ws += MAXT * sizeof(int);
    int* tm = (int*)ws;              ws += MAXT * sizeof(int);
    // contrib aliases w1t (pass2/combine no longer need w1t)
    float* contrib = (float*)w1t;

    k_init<<<1, 64, 0, stream>>>(cnt, probsum);
    k_cvt_x<<<(T_TOK * D_DIM / 8) / 256, 256, 0, stream>>>(x, xbf);
    k_cvt_wt<<<dim3(FF_DIM / 64, D_DIM / 64, 2 * E_EXP), 256, 0, stream>>>(W1, Wg, w1t, wgt);
    k_cvt_w2<<<dim3(D_DIM / 64, FF_DIM / 64, E_EXP), 256, 0, stream>>>(W2, w2t);
    k_router<<<T_TOK / 4, 256, 0, stream>>>(x, Wr, tok_e, tok_w, cnt, probsum);
    k_prefix<<<1, 64, 0, stream>>>(cnt, probsum, basep, cursor, out + (size_t)T_TOK * D_DIM,
                                   nt, te, tm);
    k_assign<<<T_TOK / 256, 256, 0, stream>>>(tok_e, tok_w, basep, cursor, row_token, row_slot, row_weight);
    k_pass1<<<dim3(FF_DIM / 128, MAXT), 512, 0, stream>>>(xbf, w1t, wgt, b1, bg, cnt, basep, row_token,
                                                          nt, te, tm, hg);
    k_pass2<<<dim3(D_DIM / 128, MAXT), 512, 0, stream>>>(hg, w2t, b2, cnt, basep, row_token, row_slot, row_weight,
                                                         nt, te, tm, contrib);
    k_combine<<<(T_TOK * D_DIM / 4) / 256, 256, 0, stream>>>(contrib, out);
}

// Round 7
// 525.657 us; speedup vs baseline: 1.3157x; 1.3157x over previous
//
#include <hip/hip_runtime.h>
#include <hip/hip_bf16.h>
#include <math.h>

#define T_TOK 4096
#define D_DIM 1024
#define E_EXP 8
#define FF_DIM 4096
#define NROWS (T_TOK * 2)
#define MAXT 40   // max m-tiles (BM=256): 8192/256 + 8

typedef unsigned short u16;
typedef unsigned int u32;
typedef __attribute__((ext_vector_type(8))) short bf16x8;
typedef __attribute__((ext_vector_type(4))) float f32x4;
typedef __attribute__((ext_vector_type(4))) short s16x4;

__device__ __forceinline__ u16 f2bf(float f) {
    union { float f; unsigned u; } v; v.f = f;
    unsigned r = v.u + 0x7FFFu + ((v.u >> 16) & 1u);
    return (u16)(r >> 16);
}

typedef const __attribute__((address_space(1))) u32* gas1_t;
typedef __attribute__((address_space(3))) u32* las3_t;
#define GLOAD16(g, l) __builtin_amdgcn_global_load_lds((gas1_t)(const void*)(g), (las3_t)(void*)(l), 16, 0, 0)
#define MFMA(a, b, c) __builtin_amdgcn_mfma_f32_16x16x32_bf16((a), (b), (c), 0, 0, 0)
#define CFENCE() asm volatile("" ::: "memory")

// ---------------- small kernels ----------------

__global__ void k_init(int* cnt, float* probsum) {
    int i = threadIdx.x;
    if (i < E_EXP) { cnt[i] = 0; probsum[i] = 0.f; }
}

__global__ __launch_bounds__(256) void k_router(
    const float* __restrict__ x, const float* __restrict__ Wr,
    int* __restrict__ tok_e, float* __restrict__ tok_w,
    int* __restrict__ cnt, float* __restrict__ probsum)
{
    __shared__ float bp[E_EXP];
    __shared__ int   bc[E_EXP];
    const int tid = threadIdx.x;
    if (tid < E_EXP) { bp[tid] = 0.f; bc[tid] = 0; }
    __syncthreads();
    const int wave = tid >> 6, lane = tid & 63;
    const int t = blockIdx.x * 4 + wave;
    const float* xt = x + (size_t)t * D_DIM;
    float a[E_EXP] = {0.f,0.f,0.f,0.f,0.f,0.f,0.f,0.f};
    for (int j = lane; j < D_DIM; j += 64) {
        float xv = xt[j];
        #pragma unroll
        for (int e = 0; e < E_EXP; e++) a[e] = fmaf(xv, Wr[e * D_DIM + j], a[e]);
    }
    #pragma unroll
    for (int e = 0; e < E_EXP; e++) {
        #pragma unroll
        for (int off = 32; off; off >>= 1) a[e] += __shfl_xor(a[e], off, 64);
    }
    if (lane == 0) {
        float mx = a[0];
        #pragma unroll
        for (int e = 1; e < E_EXP; e++) mx = fmaxf(mx, a[e]);
        float p[E_EXP], s = 0.f;
        #pragma unroll
        for (int e = 0; e < E_EXP; e++) { p[e] = expf(a[e] - mx); s += p[e]; }
        float inv = 1.f / s;
        #pragma unroll
        for (int e = 0; e < E_EXP; e++) { p[e] *= inv; atomicAdd(&bp[e], p[e]); }
        int e0 = 0; float v0 = p[0];
        #pragma unroll
        for (int e = 1; e < E_EXP; e++) if (p[e] > v0) { v0 = p[e]; e0 = e; }
        int e1 = -1; float v1 = -1.f;
        #pragma unroll
        for (int e = 0; e < E_EXP; e++) if (e != e0 && p[e] > v1) { v1 = p[e]; e1 = e; }
        float sv = v0 + v1 + 1e-6f;
        tok_e[2*t] = e0; tok_e[2*t+1] = e1;
        tok_w[2*t] = v0 / sv; tok_w[2*t+1] = v1 / sv;
        atomicAdd(&bc[e0], 1); atomicAdd(&bc[e1], 1);
    }
    __syncthreads();
    if (tid < E_EXP) { atomicAdd(&cnt[tid], bc[tid]); atomicAdd(&probsum[tid], bp[tid]); }
}

__global__ void k_prefix(const int* __restrict__ cnt, const float* __restrict__ probsum,
                         int* __restrict__ basep, int* __restrict__ cursor,
                         float* __restrict__ out_lb,
                         int* __restrict__ nt, int* __restrict__ te, int* __restrict__ tm)
{
    if (threadIdx.x == 0) {
        int b = 0; float lb = 0.f;
        for (int e = 0; e < E_EXP; e++) {
            basep[e] = b; b += cnt[e];
            lb += ((float)cnt[e] / (8192.f + 1e-6f)) * probsum[e];
        }
        *out_lb = lb * (float)E_EXP;
        int n1 = 0;
        for (int e = 0; e < E_EXP; e++)
            for (int m = 0; m < cnt[e]; m += 256) { te[n1] = e; tm[n1] = m; n1++; }
        *nt = n1;
    }
    if (threadIdx.x < E_EXP) cursor[threadIdx.x] = 0;
}

__global__ void k_assign(const int* __restrict__ tok_e, const float* __restrict__ tok_w,
                         const int* __restrict__ basep, int* __restrict__ cursor,
                         int* __restrict__ row_token, int* __restrict__ row_slot,
                         float* __restrict__ row_weight)
{
    int t = blockIdx.x * blockDim.x + threadIdx.x;
    if (t >= T_TOK) return;
    #pragma unroll
    for (int k = 0; k < 2; k++) {
        int e = tok_e[2*t + k];
        int pos = basep[e] + atomicAdd(&cursor[e], 1);
        row_token[pos] = t; row_slot[pos] = k; row_weight[pos] = tok_w[2*t + k];
    }
}

// ---------------- conversion kernels ----------------

__global__ __launch_bounds__(256) void k_cvt_x(const float* __restrict__ in, u16* __restrict__ out) {
    size_t i = ((size_t)blockIdx.x * 256 + threadIdx.x) * 8;
    f32x4 a = *(const f32x4*)(in + i);
    f32x4 b = *(const f32x4*)(in + i + 4);
    bf16x8 o;
    #pragma unroll
    for (int j = 0; j < 4; j++) { o[j] = (short)f2bf(a[j]); o[j + 4] = (short)f2bf(b[j]); }
    *(bf16x8*)(out + i) = o;
}

__device__ __forceinline__ void tile_transpose(const float* __restrict__ in, u16* __restrict__ out,
                                               int R, int C) {
    __shared__ u16 t[64][68];
    const int r0 = blockIdx.y * 64, c0 = blockIdx.x * 64;
    const int tid = threadIdx.x;
    const int lr = tid >> 4, lc = (tid & 15) * 4;
    #pragma unroll
    for (int i = 0; i < 4; i++) {
        const int r = lr + i * 16;
        f32x4 v = *(const f32x4*)(in + (size_t)(r0 + r) * C + c0 + lc);
        s16x4 w;
        #pragma unroll
        for (int j = 0; j < 4; j++) w[j] = (short)f2bf(v[j]);
        *(s16x4*)&t[r][lc] = w;
    }
    __syncthreads();
    #pragma unroll
    for (int i = 0; i < 4; i++) {
        const int c = lr + i * 16;
        s16x4 w;
        #pragma unroll
        for (int j = 0; j < 4; j++) w[j] = (short)t[lc + j][c];
        *(s16x4*)(out + (size_t)(c0 + c) * R + r0 + lc) = w;
    }
}

__global__ __launch_bounds__(256) void k_cvt_wt(const float* __restrict__ W1, const float* __restrict__ Wg,
                                                u16* __restrict__ w1t, u16* __restrict__ wgt) {
    const int z = blockIdx.z;
    const float* in;
    u16* out;
    if (z < E_EXP) { in = W1 + (size_t)z * D_DIM * FF_DIM; out = w1t + (size_t)z * D_DIM * FF_DIM; }
    else { in = Wg + (size_t)(z - E_EXP) * D_DIM * FF_DIM; out = wgt + (size_t)(z - E_EXP) * D_DIM * FF_DIM; }
    tile_transpose(in, out, D_DIM, FF_DIM);
}

__global__ __launch_bounds__(256) void k_cvt_w2(const float* __restrict__ W2, u16* __restrict__ w2t) {
    const int z = blockIdx.z;
    tile_transpose(W2 + (size_t)z * FF_DIM * D_DIM, w2t + (size_t)z * FF_DIM * D_DIM, FF_DIM, D_DIM);
}

// ---------------- pass 1: hg = silu(x@Wg) * (x@W1) ----------------
// EXACT R5 structure (row-major [row][32] LDS, 16-line/instr staging, 3 buffers,
// depth-2 prefetch, counted vmcnt) with ONE change: swizzle sigma(r) = (r>>1)&3
// instead of r&3. Bank math: lanes fr=0..15 -> bank 16*(fr&1) + 4*((fr>>1)&3 ^ q):
// 8 distinct 16B-slots x 2 lanes = 2-way (free) vs R5's 4 slots x 4 = 4-way.
// Same involution on store (pre-permuted global chunk) and read.

__global__ __launch_bounds__(512, 2) void k_pass1(
    const u16* __restrict__ xbf,
    const u16* __restrict__ w1t, const u16* __restrict__ wgt,
    const float* __restrict__ b1v, const float* __restrict__ bgv,
    const int* __restrict__ cnt, const int* __restrict__ basep,
    const int* __restrict__ row_token,
    const int* __restrict__ ntp, const int* __restrict__ te, const int* __restrict__ tm,
    u16* __restrict__ hg)
{
    const int ty = blockIdx.y;
    if (ty >= *ntp) return;
    const int e = te[ty];
    const int m0 = tm[ty];
    const int count = cnt[e];
    const int rbase = basep[e];
    const int n0 = blockIdx.x * 128;

    // per buffer (16384 elems = 32 KB): A[256x32] @0, Bh[128x32] @8192, Bg[128x32] @12288
    __shared__ __align__(16) u16 LDS[3 * 16384];

    const int tid = threadIdx.x;
    const int l = tid & 63;
    const int w = tid >> 6;

    // staging geometry: thread covers row = tid>>2, chunk-slot tid&3 (chunks of 8 elems)
    const int srow = tid >> 2;
    const int sw0 = ((tid & 3) ^ ((srow >> 1) & 3)) * 8;   // pre-permuted global chunk
    int gA0 = m0 + srow;        if (gA0 > count - 1) gA0 = count - 1;
    int gA1 = m0 + 128 + srow;  if (gA1 > count - 1) gA1 = count - 1;
    const u16* sA0 = xbf + (size_t)row_token[rbase + gA0] * D_DIM + sw0;
    const u16* sA1 = xbf + (size_t)row_token[rbase + gA1] * D_DIM + sw0;
    const size_t wo = ((size_t)e * FF_DIM + (size_t)(n0 + srow)) * D_DIM + sw0;
    const u16* sBh = w1t + wo;
    const u16* sBg = wgt + wo;
    const int dA0 = tid * 8, dA1 = 4096 + tid * 8, dBh = 8192 + tid * 8, dBg = 12288 + tid * 8;

    const int wm = w >> 2, wn = w & 3;     // 2M x 4N
    const int fr = l & 15, q = l >> 4;
    const int rs = (q ^ ((fr >> 1) & 3)) * 8;   // swizzled read chunk-slot offset

    f32x4 acc_h[8][2], acc_g[8][2];
    const f32x4 z4 = {0.f, 0.f, 0.f, 0.f};
    #pragma unroll
    for (int mf = 0; mf < 8; mf++)
        #pragma unroll
        for (int nf = 0; nf < 2; nf++) { acc_h[mf][nf] = z4; acc_g[mf][nf] = z4; }

    auto STAGE_A = [&](int b, int k0) {
        GLOAD16(sA0 + k0, &LDS[b * 16384 + dA0]);
        GLOAD16(sA1 + k0, &LDS[b * 16384 + dA1]);
    };
    auto STAGE_B = [&](int b, int k0) {
        GLOAD16(sBh + k0, &LDS[b * 16384 + dBh]);
        GLOAD16(sBg + k0, &LDS[b * 16384 + dBg]);
    };

    const int NT = D_DIM / 32;   // 32
    STAGE_A(0, 0); STAGE_B(0, 0);
    STAGE_A(1, 32); STAGE_B(1, 32);
    int cur = 0;
    #pragma unroll 1
    for (int t = 0; t < NT; ++t) {
        const int nx = (cur + 2 >= 3) ? cur - 1 : cur + 2;
        const int k2 = (t + 2) * 32;
        // ---- phase 0 ----
        if (t + 2 < NT) {
            STAGE_A(nx, k2);
            asm volatile("s_waitcnt vmcnt(6)" ::: "memory");
        } else if (t + 1 < NT) {
            asm volatile("s_waitcnt vmcnt(4)" ::: "memory");
        } else {
            asm volatile("s_waitcnt vmcnt(0)" ::: "memory");
        }
        __builtin_amdgcn_s_barrier();
        CFENCE();
        const int ab = cur * 16384;
        bf16x8 bh[2], bg[2], a0[4];
        #pragma unroll
        for (int nf = 0; nf < 2; nf++) {
            const int row = wn * 32 + nf * 16 + fr;
            bh[nf] = *(const bf16x8*)&LDS[ab + 8192 + row * 32 + rs];
            bg[nf] = *(const bf16x8*)&LDS[ab + 12288 + row * 32 + rs];
        }
        #pragma unroll
        for (int i = 0; i < 4; i++)
            a0[i] = *(const bf16x8*)&LDS[ab + (wm * 128 + i * 16 + fr) * 32 + rs];
        __builtin_amdgcn_s_setprio(1);
        #pragma unroll
        for (int i = 0; i < 4; i++) {
            acc_h[i][0] = MFMA(a0[i], bh[0], acc_h[i][0]);
            acc_h[i][1] = MFMA(a0[i], bh[1], acc_h[i][1]);
            acc_g[i][0] = MFMA(a0[i], bg[0], acc_g[i][0]);
            acc_g[i][1] = MFMA(a0[i], bg[1], acc_g[i][1]);
        }
        __builtin_amdgcn_s_setprio(0);
        // ---- phase 1 ----
        if (t + 2 < NT) STAGE_B(nx, k2);
        bf16x8 a1[4];
        #pragma unroll
        for (int i = 0; i < 4; i++)
            a1[i] = *(const bf16x8*)&LDS[ab + (wm * 128 + (4 + i) * 16 + fr) * 32 + rs];
        __builtin_amdgcn_s_setprio(1);
        #pragma unroll
        for (int i = 0; i < 4; i++) {
            acc_h[4 + i][0] = MFMA(a1[i], bh[0], acc_h[4 + i][0]);
            acc_h[4 + i][1] = MFMA(a1[i], bh[1], acc_h[4 + i][1]);
            acc_g[4 + i][0] = MFMA(a1[i], bg[0], acc_g[4 + i][0]);
            acc_g[4 + i][1] = MFMA(a1[i], bg[1], acc_g[4 + i][1]);
        }
        __builtin_amdgcn_s_setprio(0);
        CFENCE();
        __builtin_amdgcn_s_barrier();
        cur = (cur + 1 >= 3) ? 0 : cur + 1;
    }

    const float* b1p = b1v + (size_t)e * FF_DIM + n0;
    const float* bgp = bgv + (size_t)e * FF_DIM + n0;
    #pragma unroll
    for (int mf = 0; mf < 8; mf++) {
        const int rl = wm * 128 + mf * 16 + q * 4;
        #pragma unroll
        for (int r = 0; r < 4; r++) {
            const int g = m0 + rl + r;
            if (g < count) {
                u16* orow = hg + (size_t)(rbase + g) * FF_DIM + n0;
                #pragma unroll
                for (int nf = 0; nf < 2; nf++) {
                    const int col = wn * 32 + nf * 16 + fr;
                    float hv = acc_h[mf][nf][r] + b1p[col];
                    float gv = acc_g[mf][nf][r] + bgp[col];
                    float sig = 1.f / (1.f + expf(-gv));
                    orow[col] = f2bf(gv * sig * hv);
                }
            }
        }
    }
}

// ---------------- pass 2: contrib = w * (hg @ W2 + b2) ----------------
// BM=256, BN=128, BK=32, 8 waves (4M x 2N). Same pipeline; same corrected swizzle.

__global__ __launch_bounds__(512, 2) void k_pass2(
    const u16* __restrict__ hg,
    const u16* __restrict__ w2t, const float* __restrict__ b2v,
    const int* __restrict__ cnt, const int* __restrict__ basep,
    const int* __restrict__ row_token, const int* __restrict__ row_slot,
    const float* __restrict__ row_weight,
    const int* __restrict__ ntp, const int* __restrict__ te, const int* __restrict__ tm,
    float* __restrict__ contrib)
{
    const int ty = blockIdx.y;
    if (ty >= *ntp) return;
    const int e = te[ty];
    const int m0 = tm[ty];
    const int count = cnt[e];
    const int rbase = basep[e];
    const int n0 = blockIdx.x * 128;

    // per buffer (12288 elems = 24 KB): A[256x32] @0, B[128x32] @8192
    __shared__ __align__(16) u16 LDS[3 * 12288];

    const int tid = threadIdx.x;
    const int l = tid & 63;
    const int w = tid >> 6;

    const int srow = tid >> 2;
    const int sw0 = ((tid & 3) ^ ((srow >> 1) & 3)) * 8;
    int gA0 = m0 + srow;        if (gA0 > count - 1) gA0 = count - 1;
    int gA1 = m0 + 128 + srow;  if (gA1 > count - 1) gA1 = count - 1;
    const u16* sA0 = hg + (size_t)(rbase + gA0) * FF_DIM + sw0;
    const u16* sA1 = hg + (size_t)(rbase + gA1) * FF_DIM + sw0;
    const u16* sB  = w2t + ((size_t)e * D_DIM + (size_t)(n0 + srow)) * FF_DIM + sw0;
    const int dA0 = tid * 8, dA1 = 4096 + tid * 8, dB = 8192 + tid * 8;

    const int wm = w >> 1, wn = w & 1;     // 4M x 2N
    const int fr = l & 15, q = l >> 4;
    const int rs = (q ^ ((fr >> 1) & 3)) * 8;

    f32x4 acc[4][4];
    const f32x4 z4 = {0.f, 0.f, 0.f, 0.f};
    #pragma unroll
    for (int mf = 0; mf < 4; mf++)
        #pragma unroll
        for (int nf = 0; nf < 4; nf++) acc[mf][nf] = z4;

    auto STAGE = [&](int b, int k0) {
        GLOAD16(sA0 + k0, &LDS[b * 12288 + dA0]);
        GLOAD16(sA1 + k0, &LDS[b * 12288 + dA1]);
        GLOAD16(sB  + k0, &LDS[b * 12288 + dB]);
    };

    const int NT = FF_DIM / 32;   // 128
    STAGE(0, 0);
    STAGE(1, 32);
    int cur = 0;
    #pragma unroll 1
    for (int t = 0; t < NT; ++t) {
        const int nx = (cur + 2 >= 3) ? cur - 1 : cur + 2;
        if (t + 2 < NT) {
            STAGE(nx, (t + 2) * 32);
            asm volatile("s_waitcnt vmcnt(6)" ::: "memory");
        } else if (t + 1 < NT) {
            asm volatile("s_waitcnt vmcnt(3)" ::: "memory");
        } else {
            asm volatile("s_waitcnt vmcnt(0)" ::: "memory");
        }
        __builtin_amdgcn_s_barrier();
        CFENCE();
        const int ab = cur * 12288;
        bf16x8 a[4], bb[4];
        #pragma unroll
        for (int mf = 0; mf < 4; mf++)
            a[mf] = *(const bf16x8*)&LDS[ab + (wm * 64 + mf * 16 + fr) * 32 + rs];
        #pragma unroll
        for (int nf = 0; nf < 4; nf++)
            bb[nf] = *(const bf16x8*)&LDS[ab + 8192 + (wn * 64 + nf * 16 + fr) * 32 + rs];
        __builtin_amdgcn_s_setprio(1);
        #pragma unroll
        for (int mf = 0; mf < 4; mf++)
            #pragma unroll
            for (int nf = 0; nf < 4; nf++)
                acc[mf][nf] = MFMA(a[mf], bb[nf], acc[mf][nf]);
        __builtin_amdgcn_s_setprio(0);
        CFENCE();
        __builtin_amdgcn_s_barrier();
        cur = (cur + 1 >= 3) ? 0 : cur + 1;
    }

    const float* b2p = b2v + (size_t)e * D_DIM + n0;
    #pragma unroll
    for (int mf = 0; mf < 4; mf++) {
        const int rl = wm * 64 + mf * 16 + q * 4;
        #pragma unroll
        for (int r = 0; r < 4; r++) {
            const int g = m0 + rl + r;
            if (g < count) {
                const int token = row_token[rbase + g];
                const int slot  = row_slot[rbase + g];
                const float wgt_ = row_weight[rbase + g];
                float* orow = contrib + ((size_t)slot * T_TOK + token) * D_DIM + n0;
                #pragma unroll
                for (int nf = 0; nf < 4; nf++) {
                    const int col = wn * 64 + nf * 16 + fr;
                    orow[col] = wgt_ * (acc[mf][nf][r] + b2p[col]);
                }
            }
        }
    }
}

__global__ void k_combine(const float* __restrict__ contrib, float* __restrict__ out) {
    int i = blockIdx.x * blockDim.x + threadIdx.x;
    const f32x4* c0 = (const f32x4*)contrib;
    const f32x4* c1 = c0 + ((size_t)T_TOK * D_DIM / 4);
    f32x4* o = (f32x4*)out;
    o[i] = c0[i] + c1[i];
}

// ---------------- launch ----------------

extern "C" void kernel_launch(void* const* d_in, const int* in_sizes, int n_in,
                              void* d_out, int out_size, void* d_ws, size_t ws_size,
                              hipStream_t stream)
{
    (void)in_sizes; (void)n_in; (void)out_size; (void)ws_size;
    const float* x  = (const float*)d_in[0];
    const float* Wr = (const float*)d_in[1];
    const float* W1 = (const float*)d_in[2];
    const float* b1 = (const float*)d_in[3];
    const float* Wg = (const float*)d_in[4];
    const float* bg = (const float*)d_in[5];
    const float* W2 = (const float*)d_in[6];
    const float* b2 = (const float*)d_in[7];
    float* out = (float*)d_out;

    char* ws = (char*)d_ws;
    u16* xbf = (u16*)ws;             ws += (size_t)T_TOK * D_DIM * sizeof(u16);
    u16* w1t = (u16*)ws;             ws += (size_t)E_EXP * D_DIM * FF_DIM * sizeof(u16);
    u16* wgt = (u16*)ws;             ws += (size_t)E_EXP * D_DIM * FF_DIM * sizeof(u16);
    u16* w2t = (u16*)ws;             ws += (size_t)E_EXP * D_DIM * FF_DIM * sizeof(u16);
    u16* hg = (u16*)ws;              ws += (size_t)NROWS * FF_DIM * sizeof(u16);
    int* tok_e = (int*)ws;           ws += (size_t)T_TOK * 2 * sizeof(int);
    float* tok_w = (float*)ws;       ws += (size_t)T_TOK * 2 * sizeof(float);
    int* row_token = (int*)ws;       ws += (size_t)NROWS * sizeof(int);
    int* row_slot = (int*)ws;        ws += (size_t)NROWS * sizeof(int);
    float* row_weight = (float*)ws;  ws += (size_t)NROWS * sizeof(float);
    int* cnt = (int*)ws;             ws += 8 * sizeof(int);
    int* basep = (int*)ws;           ws += 8 * sizeof(int);
    int* cursor = (int*)ws;          ws += 8 * sizeof(int);
    float* probsum = (float*)ws;     ws += 8 * sizeof(float);
    int* nt = (int*)ws;              ws += sizeof(int);
    int* te = (int*)ws;              ws += MAXT * sizeof(int);
    int* tm = (int*)ws;              ws += MAXT * sizeof(int);
    // contrib aliases w1t (pass2/combine no longer need w1t)
    float* contrib = (float*)w1t;

    k_init<<<1, 64, 0, stream>>>(cnt, probsum);
    k_cvt_x<<<(T_TOK * D_DIM / 8) / 256, 256, 0, stream>>>(x, xbf);
    k_cvt_wt<<<dim3(FF_DIM / 64, D_DIM / 64, 2 * E_EXP), 256, 0, stream>>>(W1, Wg, w1t, wgt);
    k_cvt_w2<<<dim3(D_DIM / 64, FF_DIM / 64, E_EXP), 256, 0, stream>>>(W2, w2t);
    k_router<<<T_TOK / 4, 256, 0, stream>>>(x, Wr, tok_e, tok_w, cnt, probsum);
    k_prefix<<<1, 64, 0, stream>>>(cnt, probsum, basep, cursor, out + (size_t)T_TOK * D_DIM,
                                   nt, te, tm);
    k_assign<<<T_TOK / 256, 256, 0, stream>>>(tok_e, tok_w, basep, cursor, row_token, row_slot, row_weight);
    k_pass1<<<dim3(FF_DIM / 128, MAXT), 512, 0, stream>>>(xbf, w1t, wgt, b1, bg, cnt, basep, row_token,
                                                          nt, te, tm, hg);
    k_pass2<<<dim3(D_DIM / 128, MAXT), 512, 0, stream>>>(hg, w2t, b2, cnt, basep, row_token, row_slot, row_weight,
                                                         nt, te, tm, contrib);
    k_combine<<<(T_TOK * D_DIM / 4) / 256, 256, 0, stream>>>(contrib, out);
}